// Round 1
// baseline (250.099 us; speedup 1.0000x reference)
//
#include <hip/hip_runtime.h>

// 8 stacked 3x3 same-pad convs on independent 3x3 images == one affine map
// out = A*x + c (A: 9x9, c: 9). compose_affine builds it in d_ws each call;
// apply_affine streams 4M rows through it.
//
// R5: software-pipelined persistent apply. Each block handles ~4 tiles
// (grid-stride); the 9 nt loads for tile t+stride are issued BEFORE the
// compute phase of tile t, so HBM reads stay in flight during the
// LDS/FMA/store phases instead of idling (~50% load-pipe duty -> ~100%).
// Everything else (conflict-free 9-coprime-32 LDS layout, nt streams,
// compose kernel) unchanged from the verified R4.

typedef float v4f __attribute__((ext_vector_type(4)));

// ---------------- Kernel 1: compose the affine map --------------------------
__global__ void compose_affine(const float* __restrict__ w,   // [8,3,3] flat
                               const float* __restrict__ b,   // [8]
                               float* __restrict__ aff)       // [90]: A(81), c(9)
{
    __shared__ float W[72];
    __shared__ float B[8];
    __shared__ float A[2][81];
    __shared__ float C[2][9];
    const int t = threadIdx.x;

    if (t < 72) W[t] = w[t];
    if (t >= 72 && t < 80) B[t - 72] = b[t - 72];
    if (t < 81) A[0][t] = (t / 9 == t % 9) ? 1.0f : 0.0f;
    if (t < 9)  C[0][t] = 0.0f;
    __syncthreads();

    int cur = 0;
    for (int d = 0; d < 8; ++d) {
        if (t < 81) {
            const int i = t / 9, j = t % 9;
            const int r = i / 3, cc = i % 3;
            float acc = 0.0f;
            float accc = (j == 0) ? B[d] : 0.0f;
            #pragma unroll
            for (int k = 0; k < 9; ++k) {
                const int rr = k / 3, kc = k % 3;
                const int dr = rr - r + 1, dc = kc - cc + 1;
                float m = 0.0f;
                if (dr >= 0 && dr < 3 && dc >= 0 && dc < 3)
                    m = W[d * 9 + dr * 3 + dc];
                acc = fmaf(m, A[cur][k * 9 + j], acc);
                if (j == 0) accc = fmaf(m, C[cur][k], accc);
            }
            A[1 - cur][t] = acc;
            if (j == 0) C[1 - cur][i] = accc;
        }
        __syncthreads();
        cur = 1 - cur;
    }
    if (t < 81) aff[t] = A[cur][t];
    if (t < 9)  aff[81 + t] = C[cur][t];
}

// ---------------- Kernel 2: pipelined wave-autonomous affine apply ----------
// Tile: 256 rows = 576 v4f. Lane L loads v4f (L + 64j), j=0..8; computes rows
// L+64*jr; row read (9*row+j): 9 coprime 32 banks -> conflict-free/32 lanes.

__device__ __forceinline__ void load_tile(v4f (&r)[9], const v4f* __restrict__ in4,
                                          long long t, int L, long long n_f4)
{
    const long long base = t * 576;
    if (base + 576 <= n_f4) {
        #pragma unroll
        for (int j = 0; j < 9; ++j)
            r[j] = __builtin_nontemporal_load(in4 + base + L + (long long)j * 64);
    } else {
        #pragma unroll
        for (int j = 0; j < 9; ++j) {
            const long long g = base + L + (long long)j * 64;
            r[j] = (g < n_f4) ? __builtin_nontemporal_load(in4 + g) : (v4f)0.0f;
        }
    }
}

__global__ __launch_bounds__(64) void apply_affine(
    const v4f* __restrict__ in4,
    const float* __restrict__ aff,
    v4f* __restrict__ out4,
    long long n_f4,
    long long n_tiles)
{
    __shared__ float tile[2304];   // 9216 B
    v4f* __restrict__ t4 = (v4f*)tile;
    const int L = threadIdx.x;
    const long long stride = (long long)gridDim.x;

    long long t = blockIdx.x;
    if (t >= n_tiles) return;

    v4f r[9];
    load_tile(r, in4, t, L, n_f4);          // prologue prefetch

    for (;;) {
        const long long base = t * 576;
        const long long tn = t + stride;
        const bool more = (tn < n_tiles);

        // ---- stage in: regs (tile t) -> LDS ----
        #pragma unroll
        for (int j = 0; j < 9; ++j) t4[L + j * 64] = r[j];
        __syncthreads();

        // ---- issue next tile's loads; in flight across compute+store ----
        if (more) load_tile(r, in4, tn, L, n_f4);

        // ---- compute 4 rows per lane, in place ----
        #pragma unroll
        for (int jr = 0; jr < 4; ++jr) {
            const int row = L + jr * 64;
            float xv[9];
            #pragma unroll
            for (int j = 0; j < 9; ++j) xv[j] = tile[row * 9 + j];
            float y[9];
            #pragma unroll
            for (int i = 0; i < 9; ++i) y[i] = aff[81 + i];
            #pragma unroll
            for (int k = 0; k < 9; ++k) {
                #pragma unroll
                for (int i = 0; i < 9; ++i)
                    y[i] = fmaf(aff[i * 9 + k], xv[k], y[i]);   // aff -> SGPR (uniform)
            }
            #pragma unroll
            for (int j = 0; j < 9; ++j) tile[row * 9 + j] = y[j];
        }
        __syncthreads();

        // ---- stage out: LDS -> nt stores (per-j to keep VGPR low) ----
        if (base + 576 <= n_f4) {
            #pragma unroll
            for (int j = 0; j < 9; ++j) {
                const v4f o = t4[L + j * 64];
                __builtin_nontemporal_store(o, out4 + base + L + (long long)j * 64);
            }
        } else {
            #pragma unroll
            for (int j = 0; j < 9; ++j) {
                const long long g = base + L + (long long)j * 64;
                if (g < n_f4) {
                    const v4f o = t4[L + j * 64];
                    __builtin_nontemporal_store(o, out4 + g);
                }
            }
        }

        if (!more) break;
        t = tn;
        __syncthreads();   // all lanes done reading LDS before next stage-in
    }
}

extern "C" void kernel_launch(void* const* d_in, const int* in_sizes, int n_in,
                              void* d_out, int out_size, void* d_ws, size_t ws_size,
                              hipStream_t stream) {
    const float* x = (const float*)d_in[0];   // [N,9] fp32
    const float* w = (const float*)d_in[1];   // [8,1,1,3,3] fp32
    const float* b = (const float*)d_in[2];   // [8] fp32
    float* out = (float*)d_out;
    float* aff = (float*)d_ws;                // 90 floats

    const long long n_elems = (long long)in_sizes[0];   // 36,000,000
    const long long n_f4    = n_elems / 4;              // 9,000,000
    const long long tiles   = (n_f4 + 575) / 576;       // 15,625 (exact)

    const long long max_blocks = 4096;                  // 16 blocks/CU
    const unsigned blocks = (unsigned)((tiles < max_blocks) ? tiles : max_blocks);

    compose_affine<<<1, 128, 0, stream>>>(w, b, aff);
    apply_affine<<<dim3(blocks), dim3(64), 0, stream>>>(
        (const v4f*)x, aff, (v4f*)out, n_f4, tiles);
}